// Round 4
// baseline (131.252 us; speedup 1.0000x reference)
//
#include <hip/hip_runtime.h>
#include <hip/hip_bf16.h>
#include <cmath>

// SDYUnit: per-pixel conv chain via 32x32x16 bf16 MFMA with fp32 emulation
// (hi*hi + hi*lo + lo*hi). Activation redistribution in-register via
// v_permlane32_swap_b32 (hardened asm: fresh outputs, explicit movs, nop).
// Wave = 64 pixels (2 col-tiles of 32). Mid weights staged once in 64KB LDS.

static constexpr int Hh = 190, Ww = 190, Him = 192, Wim = 192, Nimg = 24;
static constexpr int NPIX = Nimg * Hh * Ww;       // 866,400
static constexpr int NWG  = (NPIX + 255) / 256;   // 3385

typedef __attribute__((ext_vector_type(8)))  short short8v;   // 8 bf16 (4 VGPR)
typedef __attribute__((ext_vector_type(16))) float f32x16;    // C/D frag
typedef __attribute__((ext_vector_type(4)))  unsigned int uint4v;

// fragment indices in ws (each frag = 512 shorts = 1024 B, layout lane*8+j)
static constexpr int FR_L1HI  = 0;   // +mt  (2 frags)
static constexpr int FR_L1LO  = 2;
static constexpr int FR_MIDHI = 4;   // +(L*8 + mt*4 + ks)  (32 frags)
static constexpr int FR_MIDLO = 36;
static constexpr int FR_L6HI  = 68;  // +ks  (4 frags)
static constexpr int FR_L6LO  = 72;

__device__ __forceinline__ unsigned short bf16_rne(float f) {
  unsigned u = __builtin_bit_cast(unsigned, f);
  unsigned r = u + 0x7FFFu + ((u >> 16) & 1u);
  return (unsigned short)(r >> 16);
}

__global__ __launch_bounds__(256) void prep_kernel(
    const float* __restrict__ W1, const float* __restrict__ W2,
    const float* __restrict__ W3, const float* __restrict__ W4,
    const float* __restrict__ W5, const float* __restrict__ W6,
    short* __restrict__ ws) {
  int t0 = blockIdx.x * 256 + threadIdx.x;
  int stride = gridDim.x * 256;
  // mid layers: A[row][k], row = mt*32+(lane&31), k = ks*16+(lane>>5)*8+j
  for (int idx = t0; idx < 32 * 512; idx += stride) {
    int j = idx & 7, lane = (idx >> 3) & 63, fi = idx >> 9;
    int ks = fi & 3, mt = (fi >> 2) & 1, L = fi >> 3;
    const float* W = (L == 0) ? W2 : (L == 1) ? W3 : (L == 2) ? W4 : W5;
    int g = mt * 32 + (lane & 31);
    int k = ks * 16 + (lane >> 5) * 8 + j;
    float w = W[g * 64 + k];
    unsigned short h = bf16_rne(w);
    float rsd = w - __builtin_bit_cast(float, (unsigned)h << 16);
    ws[(FR_MIDHI + fi) * 512 + (idx & 511)] = (short)h;
    ws[(FR_MIDLO + fi) * 512 + (idx & 511)] = (short)bf16_rne(rsd);
  }
  // layer 1: K=4 zero-padded to 16
  for (int idx = t0; idx < 2 * 512; idx += stride) {
    int j = idx & 7, lane = (idx >> 3) & 63, mt = idx >> 9;
    int g = mt * 32 + (lane & 31);
    int k = (lane >> 5) * 8 + j;
    float w = (k < 4) ? W1[g * 4 + k] : 0.f;
    unsigned short h = bf16_rne(w);
    float rsd = w - __builtin_bit_cast(float, (unsigned)h << 16);
    ws[(FR_L1HI + mt) * 512 + (idx & 511)] = (short)h;
    ws[(FR_L1LO + mt) * 512 + (idx & 511)] = (short)bf16_rne(rsd);
  }
  // layer 6: M=16 zero-padded to 32
  for (int idx = t0; idx < 4 * 512; idx += stride) {
    int j = idx & 7, lane = (idx >> 3) & 63, ks = idx >> 9;
    int g = lane & 31;
    int k = ks * 16 + (lane >> 5) * 8 + j;
    float w = (g < 16) ? W6[g * 64 + k] : 0.f;
    unsigned short h = bf16_rne(w);
    float rsd = w - __builtin_bit_cast(float, (unsigned)h << 16);
    ws[(FR_L6HI + ks) * 512 + (idx & 511)] = (short)h;
    ws[(FR_L6LO + ks) * 512 + (idx & 511)] = (short)bf16_rne(rsd);
  }
}

// ---------------- device helpers ----------------

__device__ __forceinline__ unsigned pk2(float a, float b) {
  return (unsigned)bf16_rne(a) | ((unsigned)bf16_rne(b) << 16);
}
__device__ __forceinline__ float lo_f(unsigned w) { return __builtin_bit_cast(float, w << 16); }
__device__ __forceinline__ float hi_f(unsigned w) { return __builtin_bit_cast(float, w & 0xFFFF0000u); }

#define PACK_QUAD(v0, v1, v2, v3, H0, H1, L0, L1)  \
  do {                                             \
    H0 = pk2(v0, v1); H1 = pk2(v2, v3);            \
    L0 = pk2((v0) - lo_f(H0), (v1) - hi_f(H0));    \
    L1 = pk2((v2) - lo_f(H1), (v3) - hi_f(H1));    \
  } while (0)

// Hardened half-swap: O0 = [A_lo31 | B_lo31], O1 = [A_hi31 | B_hi31].
// Fresh early-clobber outputs + explicit movs inside the asm block: immune to
// copy-propagation coalescing; s_nop covers any VGPR-write -> cross-lane-read
// hazard (inline asm bypasses compiler hazard insertion).
#define SWAPPAIR(O0, O1, A, B)            \
  asm("v_mov_b32 %0, %2\n\t"              \
      "v_mov_b32 %1, %3\n\t"              \
      "s_nop 1\n\t"                       \
      "v_permlane32_swap_b32 %0, %1"      \
      : "=&v"(O0), "=&v"(O1)              \
      : "v"(A), "v"(B))

__device__ __forceinline__ short8v mkfrag(unsigned a0, unsigned a1,
                                          unsigned b0, unsigned b1) {
  uint4v u = {a0, a1, b0, b1};
  return __builtin_bit_cast(short8v, u);
}

__device__ __forceinline__ f32x16 mm3(short8v ah, short8v al,
                                      short8v bh, short8v bl, f32x16 c) {
  c = __builtin_amdgcn_mfma_f32_32x32x16_bf16(ah, bh, c, 0, 0, 0);
  c = __builtin_amdgcn_mfma_f32_32x32x16_bf16(ah, bl, c, 0, 0, 0);
  c = __builtin_amdgcn_mfma_f32_32x32x16_bf16(al, bh, c, 0, 0, 0);
  return c;
}

__device__ __forceinline__ f32x16 mm3z(short8v ah, short8v al,
                                       short8v bh, short8v bl, f32x16 c) {
  return mm3(ah, al, bh, bl, c);
}

__device__ __forceinline__ void init_bias(f32x16 (&acc)[2][2], const float* bb, int b5) {
#pragma unroll
  for (int mt = 0; mt < 2; ++mt)
#pragma unroll
    for (int qd = 0; qd < 4; ++qd) {
      float4 bv = *(const float4*)(bb + mt * 32 + qd * 8 + b5 * 4);
#pragma unroll
      for (int nt = 0; nt < 2; ++nt) {
        acc[mt][nt][qd * 4 + 0] = bv.x; acc[mt][nt][qd * 4 + 1] = bv.y;
        acc[mt][nt][qd * 4 + 2] = bv.z; acc[mt][nt][qd * 4 + 3] = bv.w;
      }
    }
}

__device__ __forceinline__ void epilogue(f32x16 (&acc)[2][2],
    unsigned (&ph)[2][2][4][2], unsigned (&pl)[2][2][4][2]) {
#pragma unroll
  for (int mt = 0; mt < 2; ++mt)
#pragma unroll
    for (int nt = 0; nt < 2; ++nt)
#pragma unroll
      for (int qd = 0; qd < 4; ++qd) {
        float v0 = fmaxf(acc[mt][nt][qd * 4 + 0], 0.f);
        float v1 = fmaxf(acc[mt][nt][qd * 4 + 1], 0.f);
        float v2 = fmaxf(acc[mt][nt][qd * 4 + 2], 0.f);
        float v3 = fmaxf(acc[mt][nt][qd * 4 + 3], 0.f);
        unsigned h0, h1, l0, l1;
        PACK_QUAD(v0, v1, v2, v3, h0, h1, l0, l1);
        ph[mt][nt][qd][0] = h0; ph[mt][nt][qd][1] = h1;
        pl[mt][nt][qd][0] = l0; pl[mt][nt][qd][1] = l1;
      }
}

// B frags for K-step ks from packed previous-layer output.
__device__ __forceinline__ void buildB(int ks,
    unsigned (&ph)[2][2][4][2], unsigned (&pl)[2][2][4][2],
    short8v (&Bh)[2], short8v (&Bl)[2]) {
  const int ms = ks >> 1, qa = (ks & 1) * 2, qb = qa + 1;
#pragma unroll
  for (int nt = 0; nt < 2; ++nt) {
    unsigned h0, h2, h1, h3;
    SWAPPAIR(h0, h2, ph[ms][nt][qa][0], ph[ms][nt][qb][0]);
    SWAPPAIR(h1, h3, ph[ms][nt][qa][1], ph[ms][nt][qb][1]);
    Bh[nt] = mkfrag(h0, h1, h2, h3);
    unsigned l0, l2, l1, l3;
    SWAPPAIR(l0, l2, pl[ms][nt][qa][0], pl[ms][nt][qb][0]);
    SWAPPAIR(l1, l3, pl[ms][nt][qa][1], pl[ms][nt][qb][1]);
    Bl[nt] = mkfrag(l0, l1, l2, l3);
  }
}

__device__ __forceinline__ void mid_layer(const short* wlds, int Lbase,
    const float* bb, int lane,
    unsigned (&ph)[2][2][4][2], unsigned (&pl)[2][2][4][2]) {
  const int b5 = lane >> 5;
  f32x16 acc[2][2];
  init_bias(acc, bb, b5);
#pragma unroll
  for (int ks = 0; ks < 4; ++ks) {
    short8v Bh[2], Bl[2];
    buildB(ks, ph, pl, Bh, Bl);
#pragma unroll
    for (int mt = 0; mt < 2; ++mt) {
      short8v ah = *(const short8v*)(wlds + (Lbase + mt * 4 + ks) * 512 + lane * 8);
      short8v al = *(const short8v*)(wlds + 16384 + (Lbase + mt * 4 + ks) * 512 + lane * 8);
      acc[mt][0] = mm3(ah, al, Bh[0], Bl[0], acc[mt][0]);
      acc[mt][1] = mm3(ah, al, Bh[1], Bl[1], acc[mt][1]);
    }
  }
  epilogue(acc, ph, pl);
}

__device__ __forceinline__ float ftanh(float x) {
  float e = __expf(2.0f * x);
  return 1.0f - __fdividef(2.0f, e + 1.0f);
}

__global__ __launch_bounds__(256, 2) void fused_kernel(
    const float* __restrict__ x, const short* __restrict__ ws,
    const float* __restrict__ b1, const float* __restrict__ b2,
    const float* __restrict__ b3, const float* __restrict__ b4,
    const float* __restrict__ b5p, const float* __restrict__ b6,
    float* __restrict__ out) {
  __shared__ short wlds[32768];  // 64KB: mid-layer weight frags hi(32K) + lo(32K)
  {
    const uint4v* src = (const uint4v*)(ws + FR_MIDHI * 512);
    uint4v* dst = (uint4v*)wlds;
#pragma unroll
    for (int it = 0; it < 16; ++it)
      dst[it * 256 + threadIdx.x] = src[it * 256 + threadIdx.x];
  }
  __syncthreads();

  const int lane = threadIdx.x & 63;
  const int wave = threadIdx.x >> 6;
  const int b5 = lane >> 5, lo5 = lane & 31;
  const int wavebase = blockIdx.x * 256 + wave * 64;

  unsigned ph[2][2][4][2], pl[2][2][4][2];

  // ---------------- layer 1 (K=4 padded, via MFMA) ----------------
  {
    int p = wavebase + lane;
    int pc = p < NPIX ? p : NPIX - 1;
    unsigned jj = (unsigned)pc % 190u;
    unsigned r  = (unsigned)pc / 190u;
    unsigned ii = r % 190u, nn = r / 190u;
    const float* xp = x + ((nn * 192u + ii) * 192u + jj);
    float t0 = xp[0], t1 = xp[1], t2 = xp[192], t3 = xp[193];
    unsigned th0, th1, tl0, tl1;
    PACK_QUAD(t0, t1, t2, t3, th0, th1, tl0, tl1);
    // broadcast: B0* = lower-half pixels to both halves, B1* = upper-half
    unsigned b0h0, b1h0, b0h1, b1h1, b0l0, b1l0, b0l1, b1l1;
    SWAPPAIR(b0h0, b1h0, th0, th0);
    SWAPPAIR(b0h1, b1h1, th1, th1);
    SWAPPAIR(b0l0, b1l0, tl0, tl0);
    SWAPPAIR(b0l1, b1l1, tl1, tl1);
    short8v B0h = mkfrag(b0h0, b0h1, b0h0, b0h1), B0l = mkfrag(b0l0, b0l1, b0l0, b0l1);
    short8v B1h = mkfrag(b1h0, b1h1, b1h0, b1h1), B1l = mkfrag(b1l0, b1l1, b1l0, b1l1);
    f32x16 acc[2][2];
    init_bias(acc, b1, b5);
#pragma unroll
    for (int mt = 0; mt < 2; ++mt) {
      short8v ah = *(const short8v*)(ws + (FR_L1HI + mt) * 512 + lane * 8);
      short8v al = *(const short8v*)(ws + (FR_L1LO + mt) * 512 + lane * 8);
      acc[mt][0] = mm3(ah, al, B0h, B0l, acc[mt][0]);
      acc[mt][1] = mm3(ah, al, B1h, B1l, acc[mt][1]);
    }
    epilogue(acc, ph, pl);
  }

  // ---------------- layers 2..5 ----------------
  mid_layer(wlds, 0,  b2,  lane, ph, pl);
  mid_layer(wlds, 8,  b3,  lane, ph, pl);
  mid_layer(wlds, 16, b4,  lane, ph, pl);
  mid_layer(wlds, 24, b5p, lane, ph, pl);

  // ---------------- layer 6 (M=16 padded) + tanh + shuffle-store ----------------
  {
    f32x16 a6[2];
#pragma unroll
    for (int nt = 0; nt < 2; ++nt) {
      float4 bv0 = *(const float4*)(b6 + b5 * 4);
      float4 bv1 = *(const float4*)(b6 + 8 + b5 * 4);
      a6[nt][0] = bv0.x; a6[nt][1] = bv0.y; a6[nt][2] = bv0.z; a6[nt][3] = bv0.w;
      a6[nt][4] = bv1.x; a6[nt][5] = bv1.y; a6[nt][6] = bv1.z; a6[nt][7] = bv1.w;
#pragma unroll
      for (int rg = 8; rg < 16; ++rg) a6[nt][rg] = 0.f;
    }
#pragma unroll
    for (int ks = 0; ks < 4; ++ks) {
      short8v Bh[2], Bl[2];
      buildB(ks, ph, pl, Bh, Bl);
      short8v ah = *(const short8v*)(ws + (FR_L6HI + ks) * 512 + lane * 8);
      short8v al = *(const short8v*)(ws + (FR_L6LO + ks) * 512 + lane * 8);
      a6[0] = mm3(ah, al, Bh[0], Bl[0], a6[0]);
      a6[1] = mm3(ah, al, Bh[1], Bl[1], a6[1]);
    }
#pragma unroll
    for (int nt = 0; nt < 2; ++nt) {
      int p2 = wavebase + nt * 32 + lo5;
      if (p2 < NPIX) {
        unsigned jj = (unsigned)p2 % 190u;
        unsigned r  = (unsigned)p2 / 190u;
        unsigned ii = r % 190u, nn = r / 190u;
        int base = (int)((nn * 760u + ii * 4u) * 760u + jj * 4u);
        float4 s0, s1;
        s0.x = ftanh(a6[nt][0]); s0.y = ftanh(a6[nt][1]);
        s0.z = ftanh(a6[nt][2]); s0.w = ftanh(a6[nt][3]);
        s1.x = ftanh(a6[nt][4]); s1.y = ftanh(a6[nt][5]);
        s1.z = ftanh(a6[nt][6]); s1.w = ftanh(a6[nt][7]);
        *reinterpret_cast<float4*>(out + base + b5 * 760) = s0;        // row b5
        *reinterpret_cast<float4*>(out + base + (2 + b5) * 760) = s1;  // row b5+2
      }
    }
  }
}

extern "C" void kernel_launch(void* const* d_in, const int* in_sizes, int n_in,
                              void* d_out, int out_size, void* d_ws, size_t ws_size,
                              hipStream_t stream) {
  const float* x  = (const float*)d_in[0];
  const float* W1 = (const float*)d_in[1];
  const float* b1 = (const float*)d_in[2];
  const float* W2 = (const float*)d_in[3];
  const float* b2 = (const float*)d_in[4];
  const float* W3 = (const float*)d_in[5];
  const float* b3 = (const float*)d_in[6];
  const float* W4 = (const float*)d_in[7];
  const float* b4 = (const float*)d_in[8];
  const float* W5 = (const float*)d_in[9];
  const float* b5 = (const float*)d_in[10];
  const float* W6 = (const float*)d_in[11];
  const float* b6 = (const float*)d_in[12];

  hipLaunchKernelGGL(prep_kernel, dim3(64), dim3(256), 0, stream,
                     W1, W2, W3, W4, W5, W6, (short*)d_ws);
  hipLaunchKernelGGL(fused_kernel, dim3(NWG), dim3(256), 0, stream,
                     x, (const short*)d_ws, b1, b2, b3, b4, b5, b6, (float*)d_out);
}

// Round 5
// 108.918 us; speedup vs baseline: 1.2051x; 1.2051x over previous
//
#include <hip/hip_runtime.h>
#include <hip/hip_bf16.h>
#include <cmath>

// SDYUnit: per-pixel conv chain via 32x32x16 bf16 MFMA, fp32 emulated as
// hi*hi + hi*lo + lo*hi. In-register activation redistribution via
// v_permlane32_swap_b32. VALU-lean epilogue: v_cvt_pk_bf16_f32 packing,
// bias injected through the MFMA C operand, hi-weights in 32KB LDS,
// lo-weights from global (L1/L2-resident).

static constexpr int Hh = 190, Ww = 190, Him = 192, Wim = 192, Nimg = 24;
static constexpr int NPIX = Nimg * Hh * Ww;       // 866,400
static constexpr int NWG  = (NPIX + 255) / 256;   // 3385

typedef __attribute__((ext_vector_type(8)))  short short8v;   // 8 bf16 (4 VGPR)
typedef __attribute__((ext_vector_type(16))) float f32x16;    // C/D frag
typedef __attribute__((ext_vector_type(4)))  unsigned int uint4v;

// fragment indices in ws (each frag = 512 shorts = 1024 B, layout lane*8+j)
static constexpr int FR_L1HI  = 0;   // +mt  (2 frags)
static constexpr int FR_L1LO  = 2;
static constexpr int FR_MIDHI = 4;   // +(L*8 + mt*4 + ks)  (32 frags)
static constexpr int FR_MIDLO = 36;
static constexpr int FR_L6HI  = 68;  // +ks  (4 frags)
static constexpr int FR_L6LO  = 72;

__device__ __forceinline__ unsigned short bf16_rne(float f) {
  unsigned u = __builtin_bit_cast(unsigned, f);
  unsigned r = u + 0x7FFFu + ((u >> 16) & 1u);
  return (unsigned short)(r >> 16);
}

__global__ __launch_bounds__(256) void prep_kernel(
    const float* __restrict__ W1, const float* __restrict__ W2,
    const float* __restrict__ W3, const float* __restrict__ W4,
    const float* __restrict__ W5, const float* __restrict__ W6,
    short* __restrict__ ws) {
  int t0 = blockIdx.x * 256 + threadIdx.x;
  int stride = gridDim.x * 256;
  // mid layers: A[row][k], row = mt*32+(lane&31), k = ks*16+(lane>>5)*8+j
  for (int idx = t0; idx < 32 * 512; idx += stride) {
    int j = idx & 7, lane = (idx >> 3) & 63, fi = idx >> 9;
    int ks = fi & 3, mt = (fi >> 2) & 1, L = fi >> 3;
    const float* W = (L == 0) ? W2 : (L == 1) ? W3 : (L == 2) ? W4 : W5;
    int g = mt * 32 + (lane & 31);
    int k = ks * 16 + (lane >> 5) * 8 + j;
    float w = W[g * 64 + k];
    unsigned short h = bf16_rne(w);
    float rsd = w - __builtin_bit_cast(float, (unsigned)h << 16);
    ws[(FR_MIDHI + fi) * 512 + (idx & 511)] = (short)h;
    ws[(FR_MIDLO + fi) * 512 + (idx & 511)] = (short)bf16_rne(rsd);
  }
  // layer 1: K=4 zero-padded to 16
  for (int idx = t0; idx < 2 * 512; idx += stride) {
    int j = idx & 7, lane = (idx >> 3) & 63, mt = idx >> 9;
    int g = mt * 32 + (lane & 31);
    int k = (lane >> 5) * 8 + j;
    float w = (k < 4) ? W1[g * 4 + k] : 0.f;
    unsigned short h = bf16_rne(w);
    float rsd = w - __builtin_bit_cast(float, (unsigned)h << 16);
    ws[(FR_L1HI + mt) * 512 + (idx & 511)] = (short)h;
    ws[(FR_L1LO + mt) * 512 + (idx & 511)] = (short)bf16_rne(rsd);
  }
  // layer 6: M=16 zero-padded to 32
  for (int idx = t0; idx < 4 * 512; idx += stride) {
    int j = idx & 7, lane = (idx >> 3) & 63, ks = idx >> 9;
    int g = lane & 31;
    int k = ks * 16 + (lane >> 5) * 8 + j;
    float w = (g < 16) ? W6[g * 64 + k] : 0.f;
    unsigned short h = bf16_rne(w);
    float rsd = w - __builtin_bit_cast(float, (unsigned)h << 16);
    ws[(FR_L6HI + ks) * 512 + (idx & 511)] = (short)h;
    ws[(FR_L6LO + ks) * 512 + (idx & 511)] = (short)bf16_rne(rsd);
  }
}

// ---------------- device helpers ----------------

// packed bf16 pair, RNE, one instruction
__device__ __forceinline__ unsigned cvtpk(float a, float b) {
  unsigned r;
  asm("v_cvt_pk_bf16_f32 %0, %1, %2" : "=v"(r) : "v"(a), "v"(b));
  return r;
}
__device__ __forceinline__ float lo_f(unsigned w) { return __builtin_bit_cast(float, w << 16); }
__device__ __forceinline__ float hi_f(unsigned w) { return __builtin_bit_cast(float, w & 0xFFFF0000u); }

// lean in-place half-swap (distinct source values; nop covers VALU->permlane hazard)
#define SWAP2(A, B) \
  asm("s_nop 1\n\tv_permlane32_swap_b32 %0, %1" : "+v"(A), "+v"(B))

// hardened self-broadcast swap for layer 1 (O0/O1 fresh, explicit movs)
#define SWAPPAIR(O0, O1, A, B)            \
  asm("v_mov_b32 %0, %2\n\t"              \
      "v_mov_b32 %1, %3\n\t"              \
      "s_nop 1\n\t"                       \
      "v_permlane32_swap_b32 %0, %1"      \
      : "=&v"(O0), "=&v"(O1)              \
      : "v"(A), "v"(B))

__device__ __forceinline__ short8v mkfrag(unsigned a0, unsigned a1,
                                          unsigned b0, unsigned b1) {
  uint4v u = {a0, a1, b0, b1};
  return __builtin_bit_cast(short8v, u);
}

__device__ __forceinline__ f32x16 mm3(short8v ah, short8v al,
                                      short8v bh, short8v bl, f32x16 c) {
  c = __builtin_amdgcn_mfma_f32_32x32x16_bf16(ah, bh, c, 0, 0, 0);
  c = __builtin_amdgcn_mfma_f32_32x32x16_bf16(ah, bl, c, 0, 0, 0);
  c = __builtin_amdgcn_mfma_f32_32x32x16_bf16(al, bh, c, 0, 0, 0);
  return c;
}

__device__ __forceinline__ void epilogue(f32x16 (&acc)[2][2],
    unsigned (&ph)[2][2][4][2], unsigned (&pl)[2][2][4][2]) {
#pragma unroll
  for (int mt = 0; mt < 2; ++mt)
#pragma unroll
    for (int nt = 0; nt < 2; ++nt)
#pragma unroll
      for (int qd = 0; qd < 4; ++qd) {
        float v0 = fmaxf(acc[mt][nt][qd * 4 + 0], 0.f);
        float v1 = fmaxf(acc[mt][nt][qd * 4 + 1], 0.f);
        float v2 = fmaxf(acc[mt][nt][qd * 4 + 2], 0.f);
        float v3 = fmaxf(acc[mt][nt][qd * 4 + 3], 0.f);
        unsigned h0 = cvtpk(v0, v1), h1 = cvtpk(v2, v3);
        float r0 = v0 - lo_f(h0), r1 = v1 - hi_f(h0);
        float r2 = v2 - lo_f(h1), r3 = v3 - hi_f(h1);
        ph[mt][nt][qd][0] = h0; ph[mt][nt][qd][1] = h1;
        pl[mt][nt][qd][0] = cvtpk(r0, r1); pl[mt][nt][qd][1] = cvtpk(r2, r3);
      }
}

// B frags for K-step ks from packed previous-layer output.
__device__ __forceinline__ void buildB(int ks,
    unsigned (&ph)[2][2][4][2], unsigned (&pl)[2][2][4][2],
    short8v (&Bh)[2], short8v (&Bl)[2]) {
  const int ms = ks >> 1, qa = (ks & 1) * 2, qb = qa + 1;
#pragma unroll
  for (int nt = 0; nt < 2; ++nt) {
    unsigned h0 = ph[ms][nt][qa][0], h2 = ph[ms][nt][qb][0];
    unsigned h1 = ph[ms][nt][qa][1], h3 = ph[ms][nt][qb][1];
    SWAP2(h0, h2); SWAP2(h1, h3);
    Bh[nt] = mkfrag(h0, h1, h2, h3);
    unsigned l0 = pl[ms][nt][qa][0], l2 = pl[ms][nt][qb][0];
    unsigned l1 = pl[ms][nt][qa][1], l3 = pl[ms][nt][qb][1];
    SWAP2(l0, l2); SWAP2(l1, l3);
    Bl[nt] = mkfrag(l0, l1, l2, l3);
  }
}

__device__ __forceinline__ void mid_layer(const short* wldsHi, const short* wsLo,
    int Lbase, const float* bb, int lane,
    unsigned (&ph)[2][2][4][2], unsigned (&pl)[2][2][4][2]) {
  const int b5 = lane >> 5;
  f32x16 acc[2][2];
  // ks = 0: C operand = bias fragment (loaded via VMEM, shared by both nt)
  {
    short8v Bh[2], Bl[2];
    buildB(0, ph, pl, Bh, Bl);
#pragma unroll
    for (int mt = 0; mt < 2; ++mt) {
      f32x16 bf;
#pragma unroll
      for (int qd = 0; qd < 4; ++qd) {
        float4 bv = *(const float4*)(bb + mt * 32 + qd * 8 + b5 * 4);
        bf[qd * 4 + 0] = bv.x; bf[qd * 4 + 1] = bv.y;
        bf[qd * 4 + 2] = bv.z; bf[qd * 4 + 3] = bv.w;
      }
      short8v ah = *(const short8v*)(wldsHi + (Lbase + mt * 4) * 512 + lane * 8);
      short8v al = *(const short8v*)(wsLo + (Lbase + mt * 4) * 512 + lane * 8);
#pragma unroll
      for (int nt = 0; nt < 2; ++nt) {
        acc[mt][nt] = __builtin_amdgcn_mfma_f32_32x32x16_bf16(ah, Bh[nt], bf, 0, 0, 0);
        acc[mt][nt] = __builtin_amdgcn_mfma_f32_32x32x16_bf16(ah, Bl[nt], acc[mt][nt], 0, 0, 0);
        acc[mt][nt] = __builtin_amdgcn_mfma_f32_32x32x16_bf16(al, Bh[nt], acc[mt][nt], 0, 0, 0);
      }
    }
  }
#pragma unroll
  for (int ks = 1; ks < 4; ++ks) {
    short8v Bh[2], Bl[2];
    buildB(ks, ph, pl, Bh, Bl);
#pragma unroll
    for (int mt = 0; mt < 2; ++mt) {
      short8v ah = *(const short8v*)(wldsHi + (Lbase + mt * 4 + ks) * 512 + lane * 8);
      short8v al = *(const short8v*)(wsLo + (Lbase + mt * 4 + ks) * 512 + lane * 8);
      acc[mt][0] = mm3(ah, al, Bh[0], Bl[0], acc[mt][0]);
      acc[mt][1] = mm3(ah, al, Bh[1], Bl[1], acc[mt][1]);
    }
  }
  epilogue(acc, ph, pl);
}

__device__ __forceinline__ float ftanh(float x) {
  float e = __expf(2.0f * x);
  return 1.0f - __fdividef(2.0f, e + 1.0f);
}

__global__ __launch_bounds__(256, 3) void fused_kernel(
    const float* __restrict__ x, const short* __restrict__ ws,
    const float* __restrict__ b1, const float* __restrict__ b2,
    const float* __restrict__ b3, const float* __restrict__ b4,
    const float* __restrict__ b5p, const float* __restrict__ b6,
    float* __restrict__ out) {
  __shared__ short wldsHi[16384];  // 32KB: mid-layer hi-weight frags
  {
    const uint4v* src = (const uint4v*)(ws + FR_MIDHI * 512);
    uint4v* dst = (uint4v*)wldsHi;
#pragma unroll
    for (int it = 0; it < 8; ++it)
      dst[it * 256 + threadIdx.x] = src[it * 256 + threadIdx.x];
  }
  __syncthreads();

  const int lane = threadIdx.x & 63;
  const int wave = threadIdx.x >> 6;
  const int b5 = lane >> 5, lo5 = lane & 31;
  const int wavebase = blockIdx.x * 256 + wave * 64;
  const short* wsLo = ws + FR_MIDLO * 512;

  unsigned ph[2][2][4][2], pl[2][2][4][2];

  // ---------------- layer 1 (K=4 padded, via MFMA) ----------------
  {
    int p = wavebase + lane;
    int pc = p < NPIX ? p : NPIX - 1;
    unsigned jj = (unsigned)pc % 190u;
    unsigned r  = (unsigned)pc / 190u;
    unsigned ii = r % 190u, nn = r / 190u;
    const float* xp = x + ((nn * 192u + ii) * 192u + jj);
    float t0 = xp[0], t1 = xp[1], t2 = xp[192], t3 = xp[193];
    unsigned th0 = cvtpk(t0, t1), th1 = cvtpk(t2, t3);
    float r0 = t0 - lo_f(th0), r1 = t1 - hi_f(th0);
    float r2 = t2 - lo_f(th1), r3 = t3 - hi_f(th1);
    unsigned tl0 = cvtpk(r0, r1), tl1 = cvtpk(r2, r3);
    // broadcast: B0* = lower-half pixels to both halves, B1* = upper-half
    unsigned b0h0, b1h0, b0h1, b1h1, b0l0, b1l0, b0l1, b1l1;
    SWAPPAIR(b0h0, b1h0, th0, th0);
    SWAPPAIR(b0h1, b1h1, th1, th1);
    SWAPPAIR(b0l0, b1l0, tl0, tl0);
    SWAPPAIR(b0l1, b1l1, tl1, tl1);
    short8v B0h = mkfrag(b0h0, b0h1, b0h0, b0h1), B0l = mkfrag(b0l0, b0l1, b0l0, b0l1);
    short8v B1h = mkfrag(b1h0, b1h1, b1h0, b1h1), B1l = mkfrag(b1l0, b1l1, b1l0, b1l1);
    f32x16 acc[2][2];
#pragma unroll
    for (int mt = 0; mt < 2; ++mt) {
      f32x16 bf;
#pragma unroll
      for (int qd = 0; qd < 4; ++qd) {
        float4 bv = *(const float4*)(b1 + mt * 32 + qd * 8 + b5 * 4);
        bf[qd * 4 + 0] = bv.x; bf[qd * 4 + 1] = bv.y;
        bf[qd * 4 + 2] = bv.z; bf[qd * 4 + 3] = bv.w;
      }
      short8v ah = *(const short8v*)(ws + (FR_L1HI + mt) * 512 + lane * 8);
      short8v al = *(const short8v*)(ws + (FR_L1LO + mt) * 512 + lane * 8);
      acc[mt][0] = __builtin_amdgcn_mfma_f32_32x32x16_bf16(ah, B0h, bf, 0, 0, 0);
      acc[mt][0] = __builtin_amdgcn_mfma_f32_32x32x16_bf16(ah, B0l, acc[mt][0], 0, 0, 0);
      acc[mt][0] = __builtin_amdgcn_mfma_f32_32x32x16_bf16(al, B0h, acc[mt][0], 0, 0, 0);
      acc[mt][1] = __builtin_amdgcn_mfma_f32_32x32x16_bf16(ah, B1h, bf, 0, 0, 0);
      acc[mt][1] = __builtin_amdgcn_mfma_f32_32x32x16_bf16(ah, B1l, acc[mt][1], 0, 0, 0);
      acc[mt][1] = __builtin_amdgcn_mfma_f32_32x32x16_bf16(al, B1h, acc[mt][1], 0, 0, 0);
    }
    epilogue(acc, ph, pl);
  }

  // ---------------- layers 2..5 ----------------
  mid_layer(wldsHi, wsLo, 0,  b2,  lane, ph, pl);
  mid_layer(wldsHi, wsLo, 8,  b3,  lane, ph, pl);
  mid_layer(wldsHi, wsLo, 16, b4,  lane, ph, pl);
  mid_layer(wldsHi, wsLo, 24, b5p, lane, ph, pl);

  // ---------------- layer 6 (M=16 padded) + tanh + shuffle-store ----------------
  {
    f32x16 c6;
#pragma unroll
    for (int qd = 0; qd < 2; ++qd) {
      float4 bv = *(const float4*)(b6 + qd * 8 + b5 * 4);
      c6[qd * 4 + 0] = bv.x; c6[qd * 4 + 1] = bv.y;
      c6[qd * 4 + 2] = bv.z; c6[qd * 4 + 3] = bv.w;
    }
#pragma unroll
    for (int rg = 8; rg < 16; ++rg) c6[rg] = 0.f;
    f32x16 a6[2];
    {
      short8v Bh[2], Bl[2];
      buildB(0, ph, pl, Bh, Bl);
      short8v ah = *(const short8v*)(ws + (FR_L6HI + 0) * 512 + lane * 8);
      short8v al = *(const short8v*)(ws + (FR_L6LO + 0) * 512 + lane * 8);
#pragma unroll
      for (int nt = 0; nt < 2; ++nt) {
        a6[nt] = __builtin_amdgcn_mfma_f32_32x32x16_bf16(ah, Bh[nt], c6, 0, 0, 0);
        a6[nt] = __builtin_amdgcn_mfma_f32_32x32x16_bf16(ah, Bl[nt], a6[nt], 0, 0, 0);
        a6[nt] = __builtin_amdgcn_mfma_f32_32x32x16_bf16(al, Bh[nt], a6[nt], 0, 0, 0);
      }
    }
#pragma unroll
    for (int ks = 1; ks < 4; ++ks) {
      short8v Bh[2], Bl[2];
      buildB(ks, ph, pl, Bh, Bl);
      short8v ah = *(const short8v*)(ws + (FR_L6HI + ks) * 512 + lane * 8);
      short8v al = *(const short8v*)(ws + (FR_L6LO + ks) * 512 + lane * 8);
      a6[0] = mm3(ah, al, Bh[0], Bl[0], a6[0]);
      a6[1] = mm3(ah, al, Bh[1], Bl[1], a6[1]);
    }
#pragma unroll
    for (int nt = 0; nt < 2; ++nt) {
      int p2 = wavebase + nt * 32 + lo5;
      if (p2 < NPIX) {
        unsigned jj = (unsigned)p2 % 190u;
        unsigned r  = (unsigned)p2 / 190u;
        unsigned ii = r % 190u, nn = r / 190u;
        int base = (int)((nn * 760u + ii * 4u) * 760u + jj * 4u);
        float4 s0, s1;
        s0.x = ftanh(a6[nt][0]); s0.y = ftanh(a6[nt][1]);
        s0.z = ftanh(a6[nt][2]); s0.w = ftanh(a6[nt][3]);
        s1.x = ftanh(a6[nt][4]); s1.y = ftanh(a6[nt][5]);
        s1.z = ftanh(a6[nt][6]); s1.w = ftanh(a6[nt][7]);
        *reinterpret_cast<float4*>(out + base + b5 * 760) = s0;        // row b5
        *reinterpret_cast<float4*>(out + base + (2 + b5) * 760) = s1;  // row b5+2
      }
    }
  }
}

extern "C" void kernel_launch(void* const* d_in, const int* in_sizes, int n_in,
                              void* d_out, int out_size, void* d_ws, size_t ws_size,
                              hipStream_t stream) {
  const float* x  = (const float*)d_in[0];
  const float* W1 = (const float*)d_in[1];
  const float* b1 = (const float*)d_in[2];
  const float* W2 = (const float*)d_in[3];
  const float* b2 = (const float*)d_in[4];
  const float* W3 = (const float*)d_in[5];
  const float* b3 = (const float*)d_in[6];
  const float* W4 = (const float*)d_in[7];
  const float* b4 = (const float*)d_in[8];
  const float* W5 = (const float*)d_in[9];
  const float* b5 = (const float*)d_in[10];
  const float* W6 = (const float*)d_in[11];
  const float* b6 = (const float*)d_in[12];

  hipLaunchKernelGGL(prep_kernel, dim3(64), dim3(256), 0, stream,
                     W1, W2, W3, W4, W5, W6, (short*)d_ws);
  hipLaunchKernelGGL(fused_kernel, dim3(NWG), dim3(256), 0, stream,
                     x, (const short*)d_ws, b1, b2, b3, b4, b5, b6, (float*)d_out);
}

// Round 6
// 104.278 us; speedup vs baseline: 1.2587x; 1.0445x over previous
//
#include <hip/hip_runtime.h>
#include <hip/hip_bf16.h>
#include <cmath>

// SDYUnit: per-pixel conv chain via 32x32x16 bf16 MFMA, fp32 emulated as
// hi*hi + hi*lo + lo*hi. KEY TRICK: weight k-columns are pre-permuted so the
// packed (relu+cvt_pk) accumulator registers ARE the next layer's B operand
// -- zero cross-lane ops, zero repack movs between layers.
//   B-slot (h,j) of K-step ks  <->  k' = (j&3) + 8*(2ks + (j>>2)) + 4h
//   (C reg r of lane-half h holds row (r&3)+8(r>>2)+4h; frag(ks) = regs 8(ks&1)..+7
//    of acc tile ms=ks>>1.)

static constexpr int Hh = 190, Ww = 190, Him = 192, Wim = 192, Nimg = 24;
static constexpr int NPIX = Nimg * Hh * Ww;       // 866,400
static constexpr int NWG  = (NPIX + 255) / 256;   // 3385

typedef __attribute__((ext_vector_type(8)))  short short8v;   // 8 bf16 (4 VGPR)
typedef __attribute__((ext_vector_type(16))) float f32x16;    // C/D frag
typedef __attribute__((ext_vector_type(4)))  unsigned int uint4v;

// fragment indices in ws (each frag = 512 shorts = 1024 B, layout lane*8+j)
static constexpr int FR_L1HI  = 0;   // +mt  (2 frags)
static constexpr int FR_L1LO  = 2;
static constexpr int FR_MIDHI = 4;   // +(L*8 + mt*4 + ks)  (32 frags)
static constexpr int FR_MIDLO = 36;
static constexpr int FR_L6HI  = 68;  // +ks  (4 frags)
static constexpr int FR_L6LO  = 72;

__device__ __forceinline__ unsigned short bf16_rne(float f) {
  unsigned u = __builtin_bit_cast(unsigned, f);
  unsigned r = u + 0x7FFFu + ((u >> 16) & 1u);
  return (unsigned short)(r >> 16);
}

__global__ __launch_bounds__(256) void prep_kernel(
    const float* __restrict__ W1, const float* __restrict__ W2,
    const float* __restrict__ W3, const float* __restrict__ W4,
    const float* __restrict__ W5, const float* __restrict__ W6,
    short* __restrict__ ws) {
  int t0 = blockIdx.x * 256 + threadIdx.x;
  int stride = gridDim.x * 256;
  // mid layers: A[row][k'], row = mt*32+(lane&31), k' per permuted slot map
  for (int idx = t0; idx < 32 * 512; idx += stride) {
    int j = idx & 7, lane = (idx >> 3) & 63, fi = idx >> 9;
    int ks = fi & 3, mt = (fi >> 2) & 1, L = fi >> 3;
    const float* W = (L == 0) ? W2 : (L == 1) ? W3 : (L == 2) ? W4 : W5;
    int g = mt * 32 + (lane & 31);
    int k = (j & 3) + 8 * (2 * ks + (j >> 2)) + 4 * (lane >> 5);
    float w = W[g * 64 + k];
    unsigned short h = bf16_rne(w);
    float rsd = w - __builtin_bit_cast(float, (unsigned)h << 16);
    ws[(FR_MIDHI + fi) * 512 + (idx & 511)] = (short)h;
    ws[(FR_MIDLO + fi) * 512 + (idx & 511)] = (short)bf16_rne(rsd);
  }
  // layer 1: taps in slots j=0..3 of BOTH halves (B zeroes the non-owner half)
  for (int idx = t0; idx < 2 * 512; idx += stride) {
    int j = idx & 7, lane = (idx >> 3) & 63, mt = idx >> 9;
    int g = mt * 32 + (lane & 31);
    float w = (j < 4) ? W1[g * 4 + j] : 0.f;
    unsigned short h = bf16_rne(w);
    float rsd = w - __builtin_bit_cast(float, (unsigned)h << 16);
    ws[(FR_L1HI + mt) * 512 + (idx & 511)] = (short)h;
    ws[(FR_L1LO + mt) * 512 + (idx & 511)] = (short)bf16_rne(rsd);
  }
  // layer 6: M=16 zero-padded to 32, same permuted k map
  for (int idx = t0; idx < 4 * 512; idx += stride) {
    int j = idx & 7, lane = (idx >> 3) & 63, ks = idx >> 9;
    int g = lane & 31;
    int k = (j & 3) + 8 * (2 * ks + (j >> 2)) + 4 * (lane >> 5);
    float w = (g < 16) ? W6[g * 64 + k] : 0.f;
    unsigned short h = bf16_rne(w);
    float rsd = w - __builtin_bit_cast(float, (unsigned)h << 16);
    ws[(FR_L6HI + ks) * 512 + (idx & 511)] = (short)h;
    ws[(FR_L6LO + ks) * 512 + (idx & 511)] = (short)bf16_rne(rsd);
  }
}

// ---------------- device helpers ----------------

// packed bf16 pair, RNE, one instruction (dst.lo = a, dst.hi = b)
__device__ __forceinline__ unsigned cvtpk(float a, float b) {
  unsigned r;
  asm("v_cvt_pk_bf16_f32 %0, %1, %2" : "=v"(r) : "v"(a), "v"(b));
  return r;
}
__device__ __forceinline__ float lo_f(unsigned w) { return __builtin_bit_cast(float, w << 16); }
__device__ __forceinline__ float hi_f(unsigned w) { return __builtin_bit_cast(float, w & 0xFFFF0000u); }

__device__ __forceinline__ short8v mkfrag(unsigned a0, unsigned a1,
                                          unsigned b0, unsigned b1) {
  uint4v u = {a0, a1, b0, b1};
  return __builtin_bit_cast(short8v, u);
}

__device__ __forceinline__ f32x16 mm3(short8v ah, short8v al,
                                      short8v bh, short8v bl, f32x16 c) {
  c = __builtin_amdgcn_mfma_f32_32x32x16_bf16(ah, bh, c, 0, 0, 0);
  c = __builtin_amdgcn_mfma_f32_32x32x16_bf16(ah, bl, c, 0, 0, 0);
  c = __builtin_amdgcn_mfma_f32_32x32x16_bf16(al, bh, c, 0, 0, 0);
  return c;
}

// relu + split-pack the accumulators straight into next-layer B fragments.
__device__ __forceinline__ void epilogue(f32x16 (&acc)[2][2],
    short8v (&fh)[2][2][2], short8v (&fl)[2][2][2]) {
#pragma unroll
  for (int mt = 0; mt < 2; ++mt)
#pragma unroll
    for (int nt = 0; nt < 2; ++nt)
#pragma unroll
      for (int s = 0; s < 2; ++s) {
        unsigned h[4], l[4];
#pragma unroll
        for (int d = 0; d < 4; ++d) {
          float v0 = fmaxf(acc[mt][nt][8 * s + 2 * d + 0], 0.f);
          float v1 = fmaxf(acc[mt][nt][8 * s + 2 * d + 1], 0.f);
          h[d] = cvtpk(v0, v1);
          l[d] = cvtpk(v0 - lo_f(h[d]), v1 - hi_f(h[d]));
        }
        fh[mt][nt][s] = mkfrag(h[0], h[1], h[2], h[3]);
        fl[mt][nt][s] = mkfrag(l[0], l[1], l[2], l[3]);
      }
}

__device__ __forceinline__ void mid_layer(const short* wldsHi, const short* wsLo,
    int Lbase, const float* bb, int lane,
    short8v (&fh)[2][2][2], short8v (&fl)[2][2][2]) {
  const int b5 = lane >> 5;
  f32x16 acc[2][2];
  // ks = 0: C operand = bias fragment (VMEM, shared by both nt)
  {
#pragma unroll
    for (int mt = 0; mt < 2; ++mt) {
      f32x16 bf;
#pragma unroll
      for (int qd = 0; qd < 4; ++qd) {
        float4 bv = *(const float4*)(bb + mt * 32 + qd * 8 + b5 * 4);
        bf[qd * 4 + 0] = bv.x; bf[qd * 4 + 1] = bv.y;
        bf[qd * 4 + 2] = bv.z; bf[qd * 4 + 3] = bv.w;
      }
      short8v ah = *(const short8v*)(wldsHi + (Lbase + mt * 4) * 512 + lane * 8);
      short8v al = *(const short8v*)(wsLo + (Lbase + mt * 4) * 512 + lane * 8);
#pragma unroll
      for (int nt = 0; nt < 2; ++nt) {
        short8v Bh = fh[0][nt][0], Bl = fl[0][nt][0];
        acc[mt][nt] = __builtin_amdgcn_mfma_f32_32x32x16_bf16(ah, Bh, bf, 0, 0, 0);
        acc[mt][nt] = __builtin_amdgcn_mfma_f32_32x32x16_bf16(ah, Bl, acc[mt][nt], 0, 0, 0);
        acc[mt][nt] = __builtin_amdgcn_mfma_f32_32x32x16_bf16(al, Bh, acc[mt][nt], 0, 0, 0);
      }
    }
  }
#pragma unroll
  for (int ks = 1; ks < 4; ++ks) {
#pragma unroll
    for (int mt = 0; mt < 2; ++mt) {
      short8v ah = *(const short8v*)(wldsHi + (Lbase + mt * 4 + ks) * 512 + lane * 8);
      short8v al = *(const short8v*)(wsLo + (Lbase + mt * 4 + ks) * 512 + lane * 8);
      acc[mt][0] = mm3(ah, al, fh[ks >> 1][0][ks & 1], fl[ks >> 1][0][ks & 1], acc[mt][0]);
      acc[mt][1] = mm3(ah, al, fh[ks >> 1][1][ks & 1], fl[ks >> 1][1][ks & 1], acc[mt][1]);
    }
  }
  epilogue(acc, fh, fl);
}

__device__ __forceinline__ float ftanh(float x) {
  float e = __expf(2.0f * x);
  return 1.0f - __fdividef(2.0f, e + 1.0f);
}

__global__ __launch_bounds__(256, 3) void fused_kernel(
    const float* __restrict__ x, const short* __restrict__ ws,
    const float* __restrict__ b1, const float* __restrict__ b2,
    const float* __restrict__ b3, const float* __restrict__ b4,
    const float* __restrict__ b5p, const float* __restrict__ b6,
    float* __restrict__ out) {
  __shared__ short wldsHi[16384];  // 32KB: mid-layer hi-weight frags
  {
    const uint4v* src = (const uint4v*)(ws + FR_MIDHI * 512);
    uint4v* dst = (uint4v*)wldsHi;
#pragma unroll
    for (int it = 0; it < 8; ++it)
      dst[it * 256 + threadIdx.x] = src[it * 256 + threadIdx.x];
  }
  __syncthreads();

  const int lane = threadIdx.x & 63;
  const int wave = threadIdx.x >> 6;
  const int b5 = lane >> 5, lo5 = lane & 31;
  const int wavebase = blockIdx.x * 256 + wave * 64;
  const short* wsLo = ws + FR_MIDLO * 512;

  short8v fh[2][2][2], fl[2][2][2];

  // ---------------- layer 1 (K=4 padded, via MFMA) ----------------
  {
    int p = wavebase + lane;
    int pc = p < NPIX ? p : NPIX - 1;
    unsigned jj = (unsigned)pc % 190u;
    unsigned r  = (unsigned)pc / 190u;
    unsigned ii = r % 190u, nn = r / 190u;
    const float* xp = x + ((nn * 192u + ii) * 192u + jj);
    float t0 = xp[0], t1 = xp[1], t2 = xp[192], t3 = xp[193];
    unsigned th0 = cvtpk(t0, t1), th1 = cvtpk(t2, t3);
    float r0 = t0 - lo_f(th0), r1 = t1 - hi_f(th0);
    float r2 = t2 - lo_f(th1), r3 = t3 - hi_f(th1);
    unsigned tl0 = cvtpk(r0, r1), tl1 = cvtpk(r2, r3);
    // B for tile nt: own-half lanes carry taps in slots j=0..3, other half 0.
    unsigned z = 0u;
    unsigned s0h0 = (b5 == 0) ? th0 : z, s0h1 = (b5 == 0) ? th1 : z;
    unsigned s0l0 = (b5 == 0) ? tl0 : z, s0l1 = (b5 == 0) ? tl1 : z;
    unsigned s1h0 = (b5 == 1) ? th0 : z, s1h1 = (b5 == 1) ? th1 : z;
    unsigned s1l0 = (b5 == 1) ? tl0 : z, s1l1 = (b5 == 1) ? tl1 : z;
    short8v B0h = mkfrag(s0h0, s0h1, s0h0, s0h1), B0l = mkfrag(s0l0, s0l1, s0l0, s0l1);
    short8v B1h = mkfrag(s1h0, s1h1, s1h0, s1h1), B1l = mkfrag(s1l0, s1l1, s1l0, s1l1);
    f32x16 acc[2][2];
#pragma unroll
    for (int mt = 0; mt < 2; ++mt) {
      f32x16 bf;
#pragma unroll
      for (int qd = 0; qd < 4; ++qd) {
        float4 bv = *(const float4*)(b1 + mt * 32 + qd * 8 + b5 * 4);
        bf[qd * 4 + 0] = bv.x; bf[qd * 4 + 1] = bv.y;
        bf[qd * 4 + 2] = bv.z; bf[qd * 4 + 3] = bv.w;
      }
      short8v ah = *(const short8v*)(ws + (FR_L1HI + mt) * 512 + lane * 8);
      short8v al = *(const short8v*)(ws + (FR_L1LO + mt) * 512 + lane * 8);
      acc[mt][0] = __builtin_amdgcn_mfma_f32_32x32x16_bf16(ah, B0h, bf, 0, 0, 0);
      acc[mt][0] = __builtin_amdgcn_mfma_f32_32x32x16_bf16(ah, B0l, acc[mt][0], 0, 0, 0);
      acc[mt][0] = __builtin_amdgcn_mfma_f32_32x32x16_bf16(al, B0h, acc[mt][0], 0, 0, 0);
      acc[mt][1] = __builtin_amdgcn_mfma_f32_32x32x16_bf16(ah, B1h, bf, 0, 0, 0);
      acc[mt][1] = __builtin_amdgcn_mfma_f32_32x32x16_bf16(ah, B1l, acc[mt][1], 0, 0, 0);
      acc[mt][1] = __builtin_amdgcn_mfma_f32_32x32x16_bf16(al, B1h, acc[mt][1], 0, 0, 0);
    }
    epilogue(acc, fh, fl);
  }

  // ---------------- layers 2..5 ----------------
  mid_layer(wldsHi, wsLo, 0,  b2,  lane, fh, fl);
  mid_layer(wldsHi, wsLo, 8,  b3,  lane, fh, fl);
  mid_layer(wldsHi, wsLo, 16, b4,  lane, fh, fl);
  mid_layer(wldsHi, wsLo, 24, b5p, lane, fh, fl);

  // ---------------- layer 6 (M=16 padded) + tanh + shuffle-store ----------------
  {
    f32x16 c6;
#pragma unroll
    for (int qd = 0; qd < 2; ++qd) {
      float4 bv = *(const float4*)(b6 + qd * 8 + b5 * 4);
      c6[qd * 4 + 0] = bv.x; c6[qd * 4 + 1] = bv.y;
      c6[qd * 4 + 2] = bv.z; c6[qd * 4 + 3] = bv.w;
    }
#pragma unroll
    for (int rg = 8; rg < 16; ++rg) c6[rg] = 0.f;
    f32x16 a6[2];
    {
      short8v ah = *(const short8v*)(ws + (FR_L6HI + 0) * 512 + lane * 8);
      short8v al = *(const short8v*)(ws + (FR_L6LO + 0) * 512 + lane * 8);
#pragma unroll
      for (int nt = 0; nt < 2; ++nt) {
        short8v Bh = fh[0][nt][0], Bl = fl[0][nt][0];
        a6[nt] = __builtin_amdgcn_mfma_f32_32x32x16_bf16(ah, Bh, c6, 0, 0, 0);
        a6[nt] = __builtin_amdgcn_mfma_f32_32x32x16_bf16(ah, Bl, a6[nt], 0, 0, 0);
        a6[nt] = __builtin_amdgcn_mfma_f32_32x32x16_bf16(al, Bh, a6[nt], 0, 0, 0);
      }
    }
#pragma unroll
    for (int ks = 1; ks < 4; ++ks) {
      short8v ah = *(const short8v*)(ws + (FR_L6HI + ks) * 512 + lane * 8);
      short8v al = *(const short8v*)(ws + (FR_L6LO + ks) * 512 + lane * 8);
      a6[0] = mm3(ah, al, fh[ks >> 1][0][ks & 1], fl[ks >> 1][0][ks & 1], a6[0]);
      a6[1] = mm3(ah, al, fh[ks >> 1][1][ks & 1], fl[ks >> 1][1][ks & 1], a6[1]);
    }
#pragma unroll
    for (int nt = 0; nt < 2; ++nt) {
      int p2 = wavebase + nt * 32 + lo5;
      if (p2 < NPIX) {
        unsigned jj = (unsigned)p2 % 190u;
        unsigned r  = (unsigned)p2 / 190u;
        unsigned ii = r % 190u, nn = r / 190u;
        int base = (int)((nn * 760u + ii * 4u) * 760u + jj * 4u);
        float4 s0, s1;
        s0.x = ftanh(a6[nt][0]); s0.y = ftanh(a6[nt][1]);
        s0.z = ftanh(a6[nt][2]); s0.w = ftanh(a6[nt][3]);
        s1.x = ftanh(a6[nt][4]); s1.y = ftanh(a6[nt][5]);
        s1.z = ftanh(a6[nt][6]); s1.w = ftanh(a6[nt][7]);
        *reinterpret_cast<float4*>(out + base + b5 * 760) = s0;        // rows 0..3: di=b5
        *reinterpret_cast<float4*>(out + base + (2 + b5) * 760) = s1;  // rows 8..11: di=2+b5
      }
    }
  }
}

extern "C" void kernel_launch(void* const* d_in, const int* in_sizes, int n_in,
                              void* d_out, int out_size, void* d_ws, size_t ws_size,
                              hipStream_t stream) {
  const float* x  = (const float*)d_in[0];
  const float* W1 = (const float*)d_in[1];
  const float* b1 = (const float*)d_in[2];
  const float* W2 = (const float*)d_in[3];
  const float* b2 = (const float*)d_in[4];
  const float* W3 = (const float*)d_in[5];
  const float* b3 = (const float*)d_in[6];
  const float* W4 = (const float*)d_in[7];
  const float* b4 = (const float*)d_in[8];
  const float* W5 = (const float*)d_in[9];
  const float* b5 = (const float*)d_in[10];
  const float* W6 = (const float*)d_in[11];
  const float* b6 = (const float*)d_in[12];

  hipLaunchKernelGGL(prep_kernel, dim3(64), dim3(256), 0, stream,
                     W1, W2, W3, W4, W5, W6, (short*)d_ws);
  hipLaunchKernelGGL(fused_kernel, dim3(NWG), dim3(256), 0, stream,
                     x, (const short*)d_ws, b1, b2, b3, b4, b5, b6, (float*)d_out);
}